// Round 1
// baseline (3989.275 us; speedup 1.0000x reference)
//
#include <hip/hip_runtime.h>
#include <hip/hip_bf16.h>
#include <math.h>

#define HIDN 256
#define GATES 1024
#define BB 8
#define LLEN 128
#define WLEN 48
#define SNUM 5
#define PLEN 32
#define NSEQ 1024
#define EMBD 256

__device__ __forceinline__ float sigf(float x){ return 1.0f/(1.0f+expf(-x)); }

// ---------------- transpose (rows x cols) -> (cols x rows) ----------------
__global__ __launch_bounds__(256) void transpose_k(const float* __restrict__ in,
    float* __restrict__ out, int rows, int cols){
  int idx = blockIdx.x*256 + threadIdx.x;
  if (idx < rows*cols){
    int r = idx / cols, c = idx - r*cols;
    out[c*rows + r] = in[idx];
  }
}

// ---------------- word LSTM gates: G = emb[tok[:,t]] @ Wih^T + h @ Whh^T + b ----------------
// M=N=1024, K=512 (256 x-part + 256 h-part). 64x64 tiles, transposed LDS, float4 ds_read.
__global__ __launch_bounds__(256) void word_gates_k(
    const int* __restrict__ tok, const float* __restrict__ emb,
    const float* __restrict__ Wih, const float* __restrict__ Whh,
    const float* __restrict__ bias, const float* __restrict__ hbuf,
    float* __restrict__ G, int t)
{
  __shared__ float As[32][68];
  __shared__ float Bs[32][68];
  const int tid = threadIdx.x;
  const int m0 = blockIdx.x*64, n0 = blockIdx.y*64;
  const int tx = tid & 15, ty = tid >> 4;
  const int lr = tid >> 3;
  const int lc = (tid & 7) * 4;
  float acc[4][4] = {};
  for (int kt = 0; kt < 16; ++kt){
    const int k0 = (kt & 7)*32;
    const bool xp = (kt < 8);
    #pragma unroll
    for (int hf = 0; hf < 2; ++hf){
      const int r = lr + hf*32;
      float4 av, bv;
      if (xp){
        const int token = tok[(m0+r)*WLEN + t];
        av = *reinterpret_cast<const float4*>(emb + (size_t)token*EMBD + k0 + lc);
      } else {
        av = *reinterpret_cast<const float4*>(hbuf + (size_t)(m0+r)*HIDN + k0 + lc);
      }
      const float* bptr = (xp ? Wih : Whh) + (size_t)(n0+r)*HIDN + k0 + lc;
      bv = *reinterpret_cast<const float4*>(bptr);
      As[lc+0][r]=av.x; As[lc+1][r]=av.y; As[lc+2][r]=av.z; As[lc+3][r]=av.w;
      Bs[lc+0][r]=bv.x; Bs[lc+1][r]=bv.y; Bs[lc+2][r]=bv.z; Bs[lc+3][r]=bv.w;
    }
    __syncthreads();
    #pragma unroll
    for (int kk = 0; kk < 32; ++kk){
      const float4 a = *reinterpret_cast<const float4*>(&As[kk][ty*4]);
      const float4 b = *reinterpret_cast<const float4*>(&Bs[kk][tx*4]);
      acc[0][0] += a.x*b.x; acc[0][1] += a.x*b.y; acc[0][2] += a.x*b.z; acc[0][3] += a.x*b.w;
      acc[1][0] += a.y*b.x; acc[1][1] += a.y*b.y; acc[1][2] += a.y*b.z; acc[1][3] += a.y*b.w;
      acc[2][0] += a.z*b.x; acc[2][1] += a.z*b.y; acc[2][2] += a.z*b.z; acc[2][3] += a.z*b.w;
      acc[3][0] += a.w*b.x; acc[3][1] += a.w*b.y; acc[3][2] += a.w*b.z; acc[3][3] += a.w*b.w;
    }
    __syncthreads();
  }
  const float4 bb = *reinterpret_cast<const float4*>(bias + n0 + tx*4);
  #pragma unroll
  for (int i = 0; i < 4; ++i){
    float4 o;
    o.x = acc[i][0]+bb.x; o.y = acc[i][1]+bb.y; o.z = acc[i][2]+bb.z; o.w = acc[i][3]+bb.w;
    *reinterpret_cast<float4*>(G + (size_t)(m0+ty*4+i)*GATES + n0 + tx*4) = o;
  }
}

// ---------------- word LSTM elementwise update ----------------
__global__ __launch_bounds__(256) void word_update_k(
  const float* __restrict__ G, float* __restrict__ h, float* __restrict__ c,
  float* __restrict__ wout, int t)
{
  int idx = blockIdx.x*256 + threadIdx.x;   // 0..262143
  int m = idx >> 8, j = idx & 255;
  const float* g = G + (size_t)m*GATES;
  float gi = g[j], gf = g[HIDN+j], gg = g[2*HIDN+j], go = g[3*HIDN+j];
  float cc = c[idx];
  cc = sigf(gf)*cc + sigf(gi)*tanhf(gg);
  float hh = sigf(go)*tanhf(cc);
  c[idx] = cc; h[idx] = hh;
  wout[(size_t)m*WLEN*HIDN + (size_t)t*HIDN + j] = hh;
}

// ---------------- generic C(MxN) = A(MxK) @ B(NxK)^T + bias, optional row gather ----------------
template<bool GATHER>
__global__ __launch_bounds__(256) void gemm_abt64_k(
  const float* __restrict__ A, const float* __restrict__ Bm,
  const float* __restrict__ bias, float* __restrict__ C,
  const int* __restrict__ gidx, int K, int N)
{
  __shared__ float As[32][68];
  __shared__ float Bs[32][68];
  const int tid = threadIdx.x;
  const int m0 = blockIdx.x*64, n0 = blockIdx.y*64;
  const int tx = tid & 15, ty = tid >> 4;
  const int lr = tid >> 3;
  const int lc = (tid & 7) * 4;
  float acc[4][4] = {};
  for (int k0 = 0; k0 < K; k0 += 32){
    #pragma unroll
    for (int hf = 0; hf < 2; ++hf){
      const int r = lr + hf*32;
      int am = m0 + r;
      if (GATHER) am = gidx[am];
      float4 av = *reinterpret_cast<const float4*>(A + (size_t)am*K + k0 + lc);
      float4 bv = *reinterpret_cast<const float4*>(Bm + (size_t)(n0+r)*K + k0 + lc);
      As[lc+0][r]=av.x; As[lc+1][r]=av.y; As[lc+2][r]=av.z; As[lc+3][r]=av.w;
      Bs[lc+0][r]=bv.x; Bs[lc+1][r]=bv.y; Bs[lc+2][r]=bv.z; Bs[lc+3][r]=bv.w;
    }
    __syncthreads();
    #pragma unroll
    for (int kk = 0; kk < 32; ++kk){
      const float4 a = *reinterpret_cast<const float4*>(&As[kk][ty*4]);
      const float4 b = *reinterpret_cast<const float4*>(&Bs[kk][tx*4]);
      acc[0][0] += a.x*b.x; acc[0][1] += a.x*b.y; acc[0][2] += a.x*b.z; acc[0][3] += a.x*b.w;
      acc[1][0] += a.y*b.x; acc[1][1] += a.y*b.y; acc[1][2] += a.y*b.z; acc[1][3] += a.y*b.w;
      acc[2][0] += a.z*b.x; acc[2][1] += a.z*b.y; acc[2][2] += a.z*b.z; acc[2][3] += a.z*b.w;
      acc[3][0] += a.w*b.x; acc[3][1] += a.w*b.y; acc[3][2] += a.w*b.z; acc[3][3] += a.w*b.w;
    }
    __syncthreads();
  }
  const float4 bb = *reinterpret_cast<const float4*>(bias + n0 + tx*4);
  #pragma unroll
  for (int i = 0; i < 4; ++i){
    float4 o;
    o.x = acc[i][0]+bb.x; o.y = acc[i][1]+bb.y; o.z = acc[i][2]+bb.z; o.w = acc[i][3]+bb.w;
    *reinterpret_cast<float4*>(C + (size_t)(m0+ty*4+i)*N + n0 + tx*4) = o;
  }
}

// ---------------- attention logits: logit[m] = sum_j ws2[j]*tanh(dot(wo[m], ws1[j])) ----------------
// M=49152 rows (64/block), all 256 j columns per block. Strided col mapping for bank-safety.
__global__ __launch_bounds__(256) void att_logits_k(
  const float* __restrict__ wout, const float* __restrict__ ws1,
  const float* __restrict__ ws2, float* __restrict__ logits)
{
  __shared__ float As[64][33];
  __shared__ float Bs[256][33];
  __shared__ float red[64][16];
  const int tid = threadIdx.x;
  const int m0 = blockIdx.x*64;
  const int tx = tid & 15, ty = tid >> 4;
  const int lr = tid >> 3;
  const int lc = (tid & 7) * 4;
  float acc[4][16] = {};
  for (int k0 = 0; k0 < 256; k0 += 32){
    #pragma unroll
    for (int hf = 0; hf < 2; ++hf){
      const int r = lr + hf*32;
      float4 av = *reinterpret_cast<const float4*>(wout + (size_t)(m0+r)*HIDN + k0 + lc);
      As[r][lc+0]=av.x; As[r][lc+1]=av.y; As[r][lc+2]=av.z; As[r][lc+3]=av.w;
    }
    #pragma unroll
    for (int h8 = 0; h8 < 8; ++h8){
      const int r = lr + h8*32;
      float4 bv = *reinterpret_cast<const float4*>(ws1 + (size_t)r*HIDN + k0 + lc);
      Bs[r][lc+0]=bv.x; Bs[r][lc+1]=bv.y; Bs[r][lc+2]=bv.z; Bs[r][lc+3]=bv.w;
    }
    __syncthreads();
    for (int kk = 0; kk < 32; ++kk){
      float a0 = As[ty*4+0][kk], a1 = As[ty*4+1][kk], a2 = As[ty*4+2][kk], a3 = As[ty*4+3][kk];
      #pragma unroll
      for (int u = 0; u < 16; ++u){
        float b = Bs[tx + 16*u][kk];
        acc[0][u] += a0*b; acc[1][u] += a1*b; acc[2][u] += a2*b; acc[3][u] += a3*b;
      }
    }
    __syncthreads();
  }
  float p0=0, p1=0, p2=0, p3=0;
  #pragma unroll
  for (int u = 0; u < 16; ++u){
    float w2 = ws2[tx + 16*u];
    p0 += w2*tanhf(acc[0][u]);
    p1 += w2*tanhf(acc[1][u]);
    p2 += w2*tanhf(acc[2][u]);
    p3 += w2*tanhf(acc[3][u]);
  }
  red[ty*4+0][tx] = p0; red[ty*4+1][tx] = p1; red[ty*4+2][tx] = p2; red[ty*4+3][tx] = p3;
  __syncthreads();
  if (tid < 64){
    float s = 0;
    #pragma unroll
    for (int q = 0; q < 16; ++q) s += red[tid][q];
    logits[m0 + tid] = s;
  }
}

// ---------------- masked softmax over W + weighted sum -> att ----------------
__global__ __launch_bounds__(256) void att_softmax_k(
  const float* __restrict__ wout, const float* __restrict__ logits,
  const int* __restrict__ tok, float* __restrict__ att)
{
  __shared__ float e[WLEN];
  __shared__ float den_s;
  const int n = blockIdx.x, j = threadIdx.x;
  if (j < WLEN){
    float l = logits[n*WLEN + j];
    if (tok[n*WLEN + j] == 0) l -= 10000.0f;
    e[j] = l;
  }
  __syncthreads();
  if (j == 0){
    float mx = -1e30f;
    for (int w = 0; w < WLEN; ++w) mx = fmaxf(mx, e[w]);
    float den = 0.f;
    for (int w = 0; w < WLEN; ++w){ float ee = expf(e[w]-mx); e[w] = ee; den += ee; }
    den_s = den;
  }
  __syncthreads();
  const float inv = 1.0f/den_s;
  float a = 0.f;
  for (int w = 0; w < WLEN; ++w)
    a += e[w]*wout[((size_t)n*WLEN + w)*HIDN + j];
  att[(size_t)n*HIDN + j] = a*inv;
}

// ---------------- small-batch recurrent LSTM (conv: 8 blocks T=128; sess: 32 blocks T=32) ----------------
__global__ __launch_bounds__(1024) void recur_lstm_k(
  const float* __restrict__ xw, const float* __restrict__ WhhT,
  float* __restrict__ out, int T)
{
  __shared__ float h_s[HIDN];
  __shared__ float c_s[HIDN];
  __shared__ float g_s[GATES];
  const int seq = blockIdx.x, tid = threadIdx.x;
  if (tid < HIDN){ h_s[tid] = 0.f; c_s[tid] = 0.f; }
  __syncthreads();
  for (int t = 0; t < T; ++t){
    float g = xw[(size_t)(seq*T + t)*GATES + tid];
    float a0=0, a1=0, a2=0, a3=0;
    #pragma unroll 4
    for (int k = 0; k < HIDN; k += 4){
      a0 += WhhT[(size_t)(k+0)*GATES + tid]*h_s[k+0];
      a1 += WhhT[(size_t)(k+1)*GATES + tid]*h_s[k+1];
      a2 += WhhT[(size_t)(k+2)*GATES + tid]*h_s[k+2];
      a3 += WhhT[(size_t)(k+3)*GATES + tid]*h_s[k+3];
    }
    g += (a0+a1)+(a2+a3);
    g_s[tid] = g;
    __syncthreads();
    if (tid < HIDN){
      float gi = g_s[tid], gf = g_s[HIDN+tid], gg = g_s[2*HIDN+tid], go = g_s[3*HIDN+tid];
      float cc = sigf(gf)*c_s[tid] + sigf(gi)*tanhf(gg);
      c_s[tid] = cc;
      float hh = sigf(go)*tanhf(cc);
      h_s[tid] = hh;
      out[(size_t)(seq*T + t)*HIDN + tid] = hh;
    }
    __syncthreads();
  }
}

// ---------------- state-transition scan (one block per b) ----------------
__global__ __launch_bounds__(256) void scan_k(
  const float* __restrict__ sess_out, const float* __restrict__ conv_out,
  const int* __restrict__ stm, const float* __restrict__ WpT,
  const float* __restrict__ bp, float* __restrict__ state)
{
  const int b = blockIdx.x, j = threadIdx.x;
  __shared__ float oc[2*HIDN];
  __shared__ int st_s[SNUM];
  float pr[SNUM];
  #pragma unroll
  for (int s = 0; s < SNUM; ++s) pr[s] = 0.f;
  for (int l = 0; l < LLEN; ++l){
    if (j < SNUM) st_s[j] = stm[((size_t)b*LLEN + l)*SNUM + j];
    __syncthreads();
    float ones = 0.f;
    float rowv[SNUM];
    #pragma unroll
    for (int s = 1; s < SNUM; ++s){
      const int sv = st_s[s];
      float vg = 0.f;
      if (sv > 0){
        int posn = sv - 1; if (posn > PLEN-1) posn = PLEN-1;
        vg = sess_out[(((size_t)(b*4 + (s-1)))*PLEN + posn)*HIDN + j];
      }
      const float val = (sv == -1) ? pr[s] : vg;
      if (sv != 0) ones += val;
      rowv[s] = vg;
      pr[s] = vg;
    }
    oc[j] = ones*0.25f;
    const int lc2 = (l == 0) ? 0 : (l-1);
    oc[HIDN + j] = conv_out[((size_t)b*LLEN + lc2)*HIDN + j];
    __syncthreads();
    float a0 = 0, a1 = 0;
    for (int k = 0; k < 2*HIDN; k += 2){
      a0 += WpT[(size_t)k*HIDN + j]*oc[k];
      a1 += WpT[(size_t)(k+1)*HIDN + j]*oc[k+1];
    }
    float n0 = a0 + a1 + bp[j];
    n0 = n0 > 0.f ? n0 : 0.f;
    float* srow = state + ((size_t)(b*LLEN + l)*SNUM)*HIDN;
    srow[j] = n0;
    #pragma unroll
    for (int s = 1; s < SNUM; ++s) srow[(size_t)s*HIDN + j] = rowv[s];
    __syncthreads();
  }
}

// ---------------- final: up = relu([att,conv]@Ws^T+bs); scores; log_softmax ----------------
__global__ __launch_bounds__(256) void final_k(
  const float* __restrict__ att, const float* __restrict__ conv_out,
  const float* __restrict__ state, const float* __restrict__ WsT,
  const float* __restrict__ bs, float* __restrict__ out)
{
  const int n = blockIdx.x, j = threadIdx.x;
  __shared__ float uc[2*HIDN];
  __shared__ float red[SNUM][4];
  uc[j] = att[(size_t)n*HIDN + j];
  uc[HIDN + j] = conv_out[(size_t)n*HIDN + j];
  __syncthreads();
  float a0 = 0, a1 = 0;
  for (int k = 0; k < 2*HIDN; k += 2){
    a0 += WsT[(size_t)k*HIDN + j]*uc[k];
    a1 += WsT[(size_t)(k+1)*HIDN + j]*uc[k+1];
  }
  float up = a0 + a1 + bs[j];
  up = fmaxf(up, 0.f);
  const int lane = j & 63, wid = j >> 6;
  for (int s = 0; s < SNUM; ++s){
    float p = state[((size_t)n*SNUM + s)*HIDN + j]*up;
    for (int off = 32; off; off >>= 1) p += __shfl_down(p, off, 64);
    if (lane == 0) red[s][wid] = p;
    __syncthreads();
  }
  if (j == 0){
    float sc[SNUM]; float mx = -1e30f;
    #pragma unroll
    for (int s = 0; s < SNUM; ++s){
      sc[s] = red[s][0]+red[s][1]+red[s][2]+red[s][3];
      mx = fmaxf(mx, sc[s]);
    }
    float den = 0.f;
    #pragma unroll
    for (int s = 0; s < SNUM; ++s) den += expf(sc[s]-mx);
    const float ls = logf(den);
    #pragma unroll
    for (int s = 0; s < SNUM; ++s) out[(size_t)n*SNUM + s] = sc[s]-mx-ls;
  }
}

// ---------------- workspace layout (floats) ----------------
static const size_t OFF_WORDOUT = 0;                       // 1024*48*256 = 12582912
static const size_t OFF_G       = 12582912;                // 1024*1024
static const size_t OFF_H       = OFF_G + 1048576;
static const size_t OFF_C       = OFF_H + 262144;
static const size_t OFF_ATT     = OFF_C + 262144;
static const size_t OFF_XWC     = OFF_ATT + 262144;        // 1024*1024
static const size_t OFF_XWS     = OFF_XWC + 1048576;       // 1024*1024
static const size_t OFF_CONV    = OFF_XWS + 1048576;       // 8*128*256
static const size_t OFF_SOUT    = OFF_CONV + 262144;       // 32*32*256
static const size_t OFF_STATE   = OFF_SOUT + 262144;       // 8*128*5*256
static const size_t OFF_WHHTC   = OFF_STATE + 1310720;
static const size_t OFF_WHHTS   = OFF_WHHTC + 262144;
static const size_t OFF_WPT     = OFF_WHHTS + 262144;      // 512*256
static const size_t OFF_WST     = OFF_WPT + 131072;
static const size_t OFF_LOG     = OFF_WST + 131072;        // 49152

extern "C" void kernel_launch(void* const* d_in, const int* in_sizes, int n_in,
                              void* d_out, int out_size, void* d_ws, size_t ws_size,
                              hipStream_t stream)
{
  const int*   tok   = (const int*)  d_in[0];
  const int*   perm  = (const int*)  d_in[2];
  const int*   stm   = (const int*)  d_in[3];
  const float* emb   = (const float*)d_in[5];
  const float* uWih  = (const float*)d_in[6];
  const float* uWhh  = (const float*)d_in[7];
  const float* ub    = (const float*)d_in[8];
  const float* ws1   = (const float*)d_in[9];
  const float* ws2   = (const float*)d_in[10];
  const float* cWih  = (const float*)d_in[11];
  const float* cWhh  = (const float*)d_in[12];
  const float* cb    = (const float*)d_in[13];
  const float* sWih  = (const float*)d_in[14];
  const float* sWhh  = (const float*)d_in[15];
  const float* sb    = (const float*)d_in[16];
  const float* Wp    = (const float*)d_in[17];
  const float* bp    = (const float*)d_in[18];
  const float* Ws    = (const float*)d_in[19];
  const float* bs    = (const float*)d_in[20];

  float* wsf      = (float*)d_ws;
  float* word_out = wsf + OFF_WORDOUT;
  float* G        = wsf + OFF_G;
  float* h        = wsf + OFF_H;
  float* c        = wsf + OFF_C;
  float* att      = wsf + OFF_ATT;
  float* xwc      = wsf + OFF_XWC;
  float* xws      = wsf + OFF_XWS;
  float* convb    = wsf + OFF_CONV;
  float* sout     = wsf + OFF_SOUT;
  float* statem   = wsf + OFF_STATE;
  float* WhhTc    = wsf + OFF_WHHTC;
  float* WhhTs    = wsf + OFF_WHHTS;
  float* WpT      = wsf + OFF_WPT;
  float* WsT      = wsf + OFF_WST;
  float* logits   = wsf + OFF_LOG;

  // zero h and c (contiguous)
  hipMemsetAsync(h, 0, 2*262144*sizeof(float), stream);

  // weight transposes
  transpose_k<<<1024, 256, 0, stream>>>(cWhh, WhhTc, 1024, 256);
  transpose_k<<<1024, 256, 0, stream>>>(sWhh, WhhTs, 1024, 256);
  transpose_k<<<512, 256, 0, stream>>>(Wp, WpT, 256, 512);
  transpose_k<<<512, 256, 0, stream>>>(Ws, WsT, 256, 512);

  // word-level LSTM (48 sequential steps over 1024 parallel sequences)
  for (int t = 0; t < WLEN; ++t){
    word_gates_k<<<dim3(16,16), 256, 0, stream>>>(tok, emb, uWih, uWhh, ub, h, G, t);
    word_update_k<<<1024, 256, 0, stream>>>(G, h, c, word_out, t);
  }

  // attention
  att_logits_k<<<768, 256, 0, stream>>>(word_out, ws1, ws2, logits);
  att_softmax_k<<<1024, 256, 0, stream>>>(word_out, logits, tok, att);

  // x-parts of conv/session LSTMs (bias folded in)
  gemm_abt64_k<false><<<dim3(16,16), 256, 0, stream>>>(att, cWih, cb, xwc, (const int*)nullptr, 256, 1024);
  gemm_abt64_k<true ><<<dim3(16,16), 256, 0, stream>>>(att, sWih, sb, xws, perm, 256, 1024);

  // recurrent parts
  recur_lstm_k<<<8, 1024, 0, stream>>>(xwc, WhhTc, convb, 128);
  recur_lstm_k<<<32, 1024, 0, stream>>>(xws, WhhTs, sout, 32);

  // state-transition scan
  scan_k<<<8, 256, 0, stream>>>(sout, convb, stm, WpT, bp, statem);

  // final projection + scores + log_softmax
  final_k<<<1024, 256, 0, stream>>>(att, convb, statem, WsT, bs, (float*)d_out);
}